// Round 3
// baseline (340.078 us; speedup 1.0000x reference)
//
#include <hip/hip_runtime.h>
#include <hip/hip_bf16.h>
#include <cmath>

// PSNR + 3D-SSIM, pred/gt (N=4, C=16->D, H=512, W=512) f32.
// R3: K1 1px/thread (64-float arrays, ~100 VGPR, no spill) writing
//     bf16x2-packed pairs (S,D) and (S2,D2) as u32;
//     K2 two float2 LDS passes (b64 ds ops, 2 fields per read),
//     W-blur = thread-owns-8-x sliding window (b64 floor, no conflicts).

#define NB 4
#define DD 16
#define HH 512
#define WW 512
#define SLICE (HH * WW)   // 2^18
#define VOL (DD * SLICE)
#define C1F 0.0001f
#define C2F 0.0009f

struct GW { float g[11]; };

__device__ inline float blo(unsigned v) {  // low bf16 -> f32 (exact)
  union { unsigned u; float f; } c; c.u = v << 16; return c.f;
}
__device__ inline float bhi(unsigned v) {  // high bf16 -> f32 (exact)
  union { unsigned u; float f; } c; c.u = v & 0xFFFF0000u; return c.f;
}
__device__ inline unsigned pack_bf2(float a, float b) {  // (lo=a, hi=b), RNE
  __hip_bfloat162 t;
  t.x = __float2bfloat16(a);
  t.y = __float2bfloat16(b);
  union { __hip_bfloat162 h; unsigned u; } c; c.h = t; return c.u;
}

__device__ inline float block_sum256(float v) {
#pragma unroll
  for (int o = 32; o > 0; o >>= 1) v += __shfl_down(v, o, 64);
  __shared__ float r[4];
  if ((threadIdx.x & 63) == 0) r[threadIdx.x >> 6] = v;
  __syncthreads();
  float out = 0.f;
  if (threadIdx.x == 0) out = r[0] + r[1] + r[2] + r[3];
  __syncthreads();
  return out;
}

__global__ void zero_acc_k(float* acc) {
  if (threadIdx.x < 8) acc[threadIdx.x] = 0.f;
}

// K1: 1 (h,w) column per thread. D-blur of {S,D,S2,D2}; write (S,D) and
// (S2,D2) as bf16x2 u32. Fused PSNR partial.
__global__ __launch_bounds__(256, 4) void dblur_k(
    const float* __restrict__ pred, const float* __restrict__ gt,
    unsigned* __restrict__ P1, unsigned* __restrict__ P2,
    float* __restrict__ acc, GW gw) {
  int tid = blockIdx.x * 256 + threadIdx.x;  // 0 .. NB*SLICE
  int n = tid >> 18;
  int s = tid & (SLICE - 1);
  const float* pb = pred + (size_t)n * VOL + s;
  const float* qb = gt + (size_t)n * VOL + s;
  float S[DD], Dm[DD], S2[DD], D2[DD];
#pragma unroll
  for (int d = 0; d < DD; ++d) {
    float p = pb[d * SLICE];
    float q = qb[d * SLICE];
    float ss = p + q, dd = p - q;
    S[d] = ss; Dm[d] = dd;
    S2[d] = ss * ss; D2[d] = dd * dd;
  }
  // PSNR: sum (p-q)^2 = sum D2 (exact)
  float sd = 0.f;
#pragma unroll
  for (int d = 0; d < DD; ++d) sd += D2[d];
  float bs = block_sum256(sd);
  if (threadIdx.x == 0) atomicAdd(&acc[n], bs);
  size_t base = ((size_t)n * DD) * SLICE + s;
#pragma unroll
  for (int dout = 0; dout < DD; ++dout) {
    float a0 = 0.f, a1 = 0.f, a2 = 0.f, a3 = 0.f;
#pragma unroll
    for (int k = 0; k < 11; ++k) {
      int j = dout + k - 5; j = j < 0 ? 0 : (j > DD - 1 ? DD - 1 : j);  // compile-time
      float w = gw.g[k];
      a0 = fmaf(w, S[j], a0);
      a1 = fmaf(w, Dm[j], a1);
      a2 = fmaf(w, S2[j], a2);
      a3 = fmaf(w, D2[j], a3);
    }
    P1[base + dout * SLICE] = pack_bf2(a0, a1);
    P2[base + dout * SLICE] = pack_bf2(a2, a3);
  }
}

// K2 tile geometry
#define TTH 32
#define TTW 64
#define INH 42      // TTH+10 rows
#define INWR 74     // TTW+10 valid cols
#define LSTR 77     // float2 LDS row stride

// One blur pass: stage bf16x2 field-pair -> float2 LDS, H-blur, W-blur.
// out[8] = W-blurred float2 for this thread's 8 consecutive x in its row.
__device__ inline void pass_blur(const unsigned* __restrict__ P, size_t base,
                                 int th0, int tw0, const GW& gw,
                                 float2* tin2, float2* tmp2, float2 out[8]) {
  int tid = threadIdx.x;
  // stage 42x74 halo, clamped
  for (int i = tid; i < INH * INWR; i += 256) {
    int y = i / INWR, x = i - y * INWR;
    int gy = th0 + y - 5; gy = gy < 0 ? 0 : (gy > HH - 1 ? HH - 1 : gy);
    int gx = tw0 + x - 5; gx = gx < 0 ? 0 : (gx > WW - 1 ? WW - 1 : gx);
    unsigned v = P[base + gy * WW + gx];
    tin2[y * LSTR + x] = make_float2(blo(v), bhi(v));
  }
  __syncthreads();
  // H-blur: item = (strip of 8 rows, col); 18 b64 reads -> 8 float2 outputs
  for (int i = tid; i < 4 * INWR; i += 256) {
    int strip = i / INWR, c = i - strip * INWR;
    int r0 = strip * 8;
    float2 w[18];
#pragma unroll
    for (int k = 0; k < 18; ++k) w[k] = tin2[(r0 + k) * LSTR + c];
#pragma unroll
    for (int j = 0; j < 8; ++j) {
      float ax = 0.f, ay = 0.f;
#pragma unroll
      for (int k = 0; k < 11; ++k) {
        ax = fmaf(gw.g[k], w[j + k].x, ax);
        ay = fmaf(gw.g[k], w[j + k].y, ay);
      }
      tmp2[(r0 + j) * LSTR + c] = make_float2(ax, ay);
    }
  }
  __syncthreads();
  // W-blur: thread owns (row = tid>>3, 8 x's at xs=(tid&7)*8); 18 b64 reads
  int row = tid >> 3, xs = (tid & 7) * 8;
  float2 w[18];
#pragma unroll
  for (int k = 0; k < 18; ++k) w[k] = tmp2[row * LSTR + xs + k];
#pragma unroll
  for (int j = 0; j < 8; ++j) {
    float ax = 0.f, ay = 0.f;
#pragma unroll
    for (int k = 0; k < 11; ++k) {
      ax = fmaf(gw.g[k], w[j + k].x, ax);
      ay = fmaf(gw.g[k], w[j + k].y, ay);
    }
    out[j] = make_float2(ax, ay);
  }
}

__global__ __launch_bounds__(256) void hw_ssim_k(
    const unsigned* __restrict__ P1, const unsigned* __restrict__ P2,
    float* __restrict__ acc, GW gw) {
  __shared__ float2 tin2[INH * LSTR];
  __shared__ float2 tmp2[TTH * LSTR];
  int b = blockIdx.x;
  int tile = b & 127;
  int d = (b >> 7) & 15;
  int n = b >> 11;
  int th0 = (tile >> 3) * TTH;
  int tw0 = (tile & 7) * TTW;
  size_t base = (size_t)(n * DD + d) << 18;
  float2 r0[8], r1[8];
  pass_blur(P1, base, th0, tw0, gw, tin2, tmp2, r0);  // (S, D) blurred
  __syncthreads();
  pass_blur(P2, base, th0, tw0, gw, tin2, tmp2, r1);  // (S2, D2) blurred
  float ssum = 0.f;
#pragma unroll
  for (int j = 0; j < 8; ++j) {
    float Sb = r0[j].x, Db = r0[j].y, B1 = r1[j].x, B2 = r1[j].y;
    float SS = Sb * Sb, DDm = Db * Db;
    float m12_2 = (SS - DDm) * 0.5f;     // 2*mu1*mu2
    float msq   = (SS + DDm) * 0.5f;     // mu1^2 + mu2^2
    float Epq   = (B1 - B2) * 0.25f;     // E[pq]
    float Esum  = (B1 + B2) * 0.5f;      // E[p^2+q^2]
    float sig12_2 = 2.f * Epq - m12_2;   // 2*sigma12
    float svar    = Esum - msq;          // sigma1^2 + sigma2^2
    float num = (m12_2 + C1F) * (sig12_2 + C2F);
    float den = (msq + C1F) * (svar + C2F);
    ssum += num / den;
  }
  float bs = block_sum256(ssum);
  if (threadIdx.x == 0) atomicAdd(&acc[4 + n], bs);
}

__global__ void final_k(const float* __restrict__ acc, float* __restrict__ out) {
  if (threadIdx.x == 0 && blockIdx.x == 0) {
    double psnr = 0.0, ssim = 0.0;
    for (int n = 0; n < NB; ++n) {
      double mse = (double)acc[n] / (double)VOL;
      psnr += 10.0 * log10(1.0 / mse);
      ssim += (double)acc[4 + n] / (double)VOL;
    }
    out[0] = (float)psnr;
    out[1] = (float)ssim;
    out[2] = (float)NB;
  }
}

extern "C" void kernel_launch(void* const* d_in, const int* in_sizes, int n_in,
                              void* d_out, int out_size, void* d_ws, size_t ws_size,
                              hipStream_t stream) {
  const float* pred = (const float*)d_in[0];
  const float* gt = (const float*)d_in[1];
  unsigned* P1 = (unsigned*)d_ws;                       // NB*VOL u32 = 67 MB
  unsigned* P2 = P1 + (size_t)NB * VOL;                 // NB*VOL u32 = 67 MB
  float* acc = (float*)(P2 + (size_t)NB * VOL);
  GW gw;
  double t[11], s = 0.0;
  for (int i = 0; i < 11; ++i) {
    double x = i - 5;
    t[i] = exp(-(x * x) / 4.5);
    s += t[i];
  }
  for (int i = 0; i < 11; ++i) gw.g[i] = (float)(t[i] / s);

  zero_acc_k<<<1, 64, 0, stream>>>(acc);
  dblur_k<<<NB * SLICE / 256, 256, 0, stream>>>(pred, gt, P1, P2, acc, gw);
  hw_ssim_k<<<NB * DD * 128, 256, 0, stream>>>(P1, P2, acc, gw);
  final_k<<<1, 1, 0, stream>>>(acc, (float*)d_out);
}